// Round 1
// baseline (133.245 us; speedup 1.0000x reference)
//
#include <hip/hip_runtime.h>
#include <math.h>

// ---------------- problem constants ----------------
#define HH 120
#define WW 160
#define NPTS (HH * WW)            // 19200
#define FXC 572.4114f
#define FYC 573.57043f
#define CXC 325.2611f
#define CYC 242.04899f

// chamfer tiling
#define CH_BT   64                 // threads per block (1 wave)
#define CH_T    5                  // a-points per thread
#define CH_APB  (CH_BT * CH_T)     // 320 a-points per block
#define CH_ABLK (NPTS / CH_APB)    // 60 a-blocks
#define CH_BTILE 600               // b-points per LDS tile
#define CH_SCH  (NPTS / CH_BTILE)  // 32 b-chunks

#define MASK_WGT 1.3989422804014327f   // exp(0)*inv_sqrt_2pi + 1

__device__ __forceinline__ void backproject_pt(int idx, float d,
                                               float& px, float& py, float& pz) {
    int y = idx / WW;
    int x = idx - y * WW;
    px = ((float)x - CXC) * d * (1.0f / FXC);
    py = ((float)y - CYC) * d * (1.0f / FYC);
    pz = d;
}

// ---------------- kernel 1: init per-point min buffers to +inf ----------------
__global__ void __launch_bounds__(256) init_mins_k(int* __restrict__ mins) {
    int i = blockIdx.x * 256 + threadIdx.x;
    if (i < 2 * NPTS) mins[i] = 0x7F800000;  // +inf bit pattern
}

// ---------------- kernel 2: chamfer partial mins ----------------
// grid: (CH_ABLK, CH_SCH, 2). blockIdx.z selects direction.
__global__ void __launch_bounds__(CH_BT) chamfer_partial_k(
    const float* __restrict__ depth_src, const float* __restrict__ depth_tgt,
    int* __restrict__ mins_base) {
    const float* dA;
    const float* dB;
    int* mins;
    if (blockIdx.z == 0) { dA = depth_src; dB = depth_tgt; mins = mins_base; }
    else                 { dA = depth_tgt; dB = depth_src; mins = mins_base + NPTS; }

    __shared__ float4 bp[CH_BTILE];

    const int tid = threadIdx.x;
    const int ablk = blockIdx.x;
    const int s = blockIdx.y;

    // stage b tile: (x, y, z, |b|^2)
    for (int jj = tid; jj < CH_BTILE; jj += CH_BT) {
        int j = s * CH_BTILE + jj;
        float d = dB[j];
        float px, py, pz;
        backproject_pt(j, d, px, py, pz);
        bp[jj] = make_float4(px, py, pz, fmaf(px, px, fmaf(py, py, pz * pz)));
    }

    // load a points into registers
    float ax[CH_T], ay[CH_T], az[CH_T], a2[CH_T], mn[CH_T];
#pragma unroll
    for (int t = 0; t < CH_T; ++t) {
        int i = ablk * CH_APB + t * CH_BT + tid;
        float d = dA[i];
        backproject_pt(i, d, ax[t], ay[t], az[t]);
        a2[t] = fmaf(ax[t], ax[t], fmaf(ay[t], ay[t], az[t] * az[t]));
        mn[t] = INFINITY;  // tracks min over j of (b2_j - 2*dot_j)
    }

    __syncthreads();

#pragma unroll 4
    for (int jj = 0; jj < CH_BTILE; ++jj) {
        float4 q = bp[jj];  // broadcast read, no bank conflict
#pragma unroll
        for (int t = 0; t < CH_T; ++t) {
            float dot = fmaf(ax[t], q.x, fmaf(ay[t], q.y, az[t] * q.z));
            float r = fmaf(-2.0f, dot, q.w);  // b2 - 2*dot
            mn[t] = fminf(mn[t], r);
        }
    }

    // finalize: d = max(a2 + (b2 - 2ab), 0); combine across b-chunks via atomicMin.
    // max(.,0) commutes with min, and values are >= 0 so int ordering == float ordering.
#pragma unroll
    for (int t = 0; t < CH_T; ++t) {
        int i = ablk * CH_APB + t * CH_BT + tid;
        float v = fmaxf(a2[t] + mn[t], 0.0f);
        atomicMin(&mins[i], __float_as_int(v));
    }
}

// ---------------- kernel 3: chamfer reduction -> out[0] ----------------
__global__ void __launch_bounds__(256) cham_reduce_k(const int* __restrict__ mins,
                                                     float* __restrict__ out) {
    __shared__ float red[256];
    float s = 0.0f;
    for (int i = threadIdx.x; i < 2 * NPTS; i += 256) s += __int_as_float(mins[i]);
    red[threadIdx.x] = s;
    __syncthreads();
    for (int w = 128; w > 0; w >>= 1) {
        if (threadIdx.x < w) red[threadIdx.x] += red[threadIdx.x + w];
        __syncthreads();
    }
    if (threadIdx.x == 0) out[0] = red[0] * (1.0f / (float)NPTS);
}

// ---------------- kernel 4: mask loss -> out[1] ----------------
__global__ void __launch_bounds__(256) mask_loss_k(const float* __restrict__ pm,
                                                   const float* __restrict__ ms,
                                                   float* __restrict__ out) {
    __shared__ float rp[256], rn[256];
    __shared__ int cp[256], cn[256];
    float ps = 0.0f, ns = 0.0f;
    int pc = 0, nc = 0;
    for (int i = threadIdx.x; i < NPTS; i += 256) {
        float p = pm[i];
        p = fminf(fmaxf(p, 1e-7f), 1.0f - 1e-7f);
        float t = ms[i];
        if (t > 0.0f) {
            ps += -t * logf(p) * MASK_WGT;
            pc++;
        } else if (t == 0.0f) {
            ns += -logf(1.0f - p) * MASK_WGT;
            nc++;
        }
    }
    int tid = threadIdx.x;
    rp[tid] = ps; rn[tid] = ns; cp[tid] = pc; cn[tid] = nc;
    __syncthreads();
    for (int w = 128; w > 0; w >>= 1) {
        if (tid < w) {
            rp[tid] += rp[tid + w];
            rn[tid] += rn[tid + w];
            cp[tid] += cp[tid + w];
            cn[tid] += cn[tid + w];
        }
        __syncthreads();
    }
    if (tid == 0) {
        float loss = 0.0f;
        if (cp[0] > 0) loss += rp[0] / (float)cp[0];
        if (cn[0] > 0) loss += rn[0] / (float)cn[0];
        out[1] = loss;
    }
}

// ---------------- launcher ----------------
extern "C" void kernel_launch(void* const* d_in, const int* in_sizes, int n_in,
                              void* d_out, int out_size, void* d_ws, size_t ws_size,
                              hipStream_t stream) {
    const float* pred_PM  = (const float*)d_in[0];
    const float* pred_Ms  = (const float*)d_in[1];
    const float* depth_src = (const float*)d_in[2];
    const float* depth_tgt = (const float*)d_in[3];
    float* out = (float*)d_out;
    int* mins = (int*)d_ws;  // 2*NPTS ints

    init_mins_k<<<(2 * NPTS + 255) / 256, 256, 0, stream>>>(mins);
    chamfer_partial_k<<<dim3(CH_ABLK, CH_SCH, 2), CH_BT, 0, stream>>>(
        depth_src, depth_tgt, mins);
    cham_reduce_k<<<1, 256, 0, stream>>>(mins, out);
    mask_loss_k<<<1, 256, 0, stream>>>(pred_PM, pred_Ms, out);
}

// Round 2
// 84.423 us; speedup vs baseline: 1.5783x; 1.5783x over previous
//
#include <hip/hip_runtime.h>
#include <math.h>

// ---------------- problem constants ----------------
#define HH 120
#define WW 160
#define NPTS (HH * WW)            // 19200
#define FXC 572.4114f
#define FYC 573.57043f
#define CXC 325.2611f
#define CYC 242.04899f

// chamfer tiling
#define CH_BT   64                 // threads per block (1 wave)
#define CH_T    6                  // a-points per thread
#define CH_APB  (CH_BT * CH_T)     // 384 a-points per block
#define CH_ABLK (NPTS / CH_APB)    // 50 a-blocks
#define CH_BTILE 600               // b-points per LDS tile
#define CH_SCH  (NPTS / CH_BTILE)  // 32 b-chunks

#define MASK_WGT 1.3989422804014327f   // exp(0)*inv_sqrt_2pi + 1

// finalize kernel geometry
#define GB_CH 64                   // blocks doing chamfer sum
#define GB_MK 16                   // blocks doing mask loss
#define GB_TOT (GB_CH + GB_MK)
#define CH_SEG (2 * NPTS / GB_CH)  // 600 elements per chamfer block
#define MK_SEG (NPTS / GB_MK)      // 1200 elements per mask block

__device__ __forceinline__ void backproject_pt(int idx, float d,
                                               float& px, float& py, float& pz) {
    int y = idx / WW;
    int x = idx - y * WW;
    px = ((float)x - CXC) * d * (1.0f / FXC);
    py = ((float)y - CYC) * d * (1.0f / FYC);
    pz = d;
}

__device__ __forceinline__ float min3f(float a, float b, float c) {
    float d;
    asm("v_min3_f32 %0, %1, %2, %3" : "=v"(d) : "v"(a), "v"(b), "v"(c));
    return d;
}

// ---------------- kernel 1: init mins to +inf, zero accumulators ----------------
__global__ void __launch_bounds__(256) init_k(int* __restrict__ mins,
                                              int* __restrict__ accs) {
    int i = blockIdx.x * 256 + threadIdx.x;
    if (i < 2 * NPTS) mins[i] = 0x7F800000;  // +inf bit pattern
    if (i < 6) accs[i] = 0;                  // accf[3] + acci[3]
}

// ---------------- kernel 2: chamfer partial mins ----------------
// grid: (CH_ABLK, CH_SCH, 2). blockIdx.z selects direction.
__global__ void __launch_bounds__(CH_BT) chamfer_partial_k(
    const float* __restrict__ depth_src, const float* __restrict__ depth_tgt,
    int* __restrict__ mins_base) {
    const float* dA;
    const float* dB;
    int* mins;
    if (blockIdx.z == 0) { dA = depth_src; dB = depth_tgt; mins = mins_base; }
    else                 { dA = depth_tgt; dB = depth_src; mins = mins_base + NPTS; }

    __shared__ float4 bp[CH_BTILE];

    const int tid = threadIdx.x;
    const int ablk = blockIdx.x;
    const int s = blockIdx.y;

    // stage b tile: (2x, 2y, 2z, |b|^2)
    for (int jj = tid; jj < CH_BTILE; jj += CH_BT) {
        int j = s * CH_BTILE + jj;
        float d = dB[j];
        float px, py, pz;
        backproject_pt(j, d, px, py, pz);
        bp[jj] = make_float4(2.0f * px, 2.0f * py, 2.0f * pz,
                             fmaf(px, px, fmaf(py, py, pz * pz)));
    }

    // load a points into registers (negated for the fma chain)
    float nax[CH_T], nay[CH_T], naz[CH_T], a2[CH_T], mn[CH_T];
#pragma unroll
    for (int t = 0; t < CH_T; ++t) {
        int i = ablk * CH_APB + t * CH_BT + tid;
        float d = dA[i];
        float px, py, pz;
        backproject_pt(i, d, px, py, pz);
        a2[t] = fmaf(px, px, fmaf(py, py, pz * pz));
        nax[t] = -px; nay[t] = -py; naz[t] = -pz;
        mn[t] = INFINITY;  // tracks min over j of (b2_j - 2*dot_j)
    }

    __syncthreads();

    // 3 fma + 0.5 min3 per pair = 3.5 VALU ops/pair
    for (int jj = 0; jj < CH_BTILE; jj += 4) {
        float4 q0 = bp[jj + 0];
        float4 q1 = bp[jj + 1];
        float4 q2 = bp[jj + 2];
        float4 q3 = bp[jj + 3];
#pragma unroll
        for (int t = 0; t < CH_T; ++t) {
            float r0 = fmaf(nax[t], q0.x, fmaf(nay[t], q0.y, fmaf(naz[t], q0.z, q0.w)));
            float r1 = fmaf(nax[t], q1.x, fmaf(nay[t], q1.y, fmaf(naz[t], q1.z, q1.w)));
            float r2 = fmaf(nax[t], q2.x, fmaf(nay[t], q2.y, fmaf(naz[t], q2.z, q2.w)));
            float r3 = fmaf(nax[t], q3.x, fmaf(nay[t], q3.y, fmaf(naz[t], q3.z, q3.w)));
            mn[t] = min3f(mn[t], r0, r1);
            mn[t] = min3f(mn[t], r2, r3);
        }
    }

    // finalize: d = max(a2 + (b2 - 2ab), 0); combine across b-chunks via atomicMin.
    // max(.,0) commutes with min; values >= 0 so int ordering == float ordering.
#pragma unroll
    for (int t = 0; t < CH_T; ++t) {
        int i = ablk * CH_APB + t * CH_BT + tid;
        float v = fmaxf(a2[t] + mn[t], 0.0f);
        atomicMin(&mins[i], __float_as_int(v));
    }
}

// ---------------- kernel 3: fused reduction + mask loss -> out[0], out[1] ----------------
// accf[0]=cham_sum, accf[1]=pos_sum, accf[2]=neg_sum
// acci[0]=pos_cnt,  acci[1]=neg_cnt,  acci[2]=done_counter
__global__ void __launch_bounds__(256) finalize_k(const int* __restrict__ mins,
                                                  const float* __restrict__ pm,
                                                  const float* __restrict__ ms,
                                                  float* __restrict__ accf,
                                                  int* __restrict__ acci,
                                                  float* __restrict__ out) {
    const int b = blockIdx.x;
    const int tid = threadIdx.x;
    __shared__ float ra[256], rb[256];
    __shared__ int ca[256], cb[256];

    if (b < GB_CH) {
        // chamfer partial sum over a 600-element segment
        float s = 0.0f;
        int base = b * CH_SEG;
        for (int i = tid; i < CH_SEG; i += 256) s += __int_as_float(mins[base + i]);
        ra[tid] = s;
        __syncthreads();
        for (int w = 128; w > 0; w >>= 1) {
            if (tid < w) ra[tid] += ra[tid + w];
            __syncthreads();
        }
        if (tid == 0) atomicAdd(&accf[0], ra[0]);
    } else {
        // mask loss partial over a 1200-element segment
        int base = (b - GB_CH) * MK_SEG;
        float ps = 0.0f, ns = 0.0f;
        int pc = 0, nc = 0;
        for (int i = tid; i < MK_SEG; i += 256) {
            float p = pm[base + i];
            p = fminf(fmaxf(p, 1e-7f), 1.0f - 1e-7f);
            float t = ms[base + i];
            if (t > 0.0f) {
                ps += -t * logf(p) * MASK_WGT;
                pc++;
            } else if (t == 0.0f) {
                ns += -logf(1.0f - p) * MASK_WGT;
                nc++;
            }
        }
        ra[tid] = ps; rb[tid] = ns; ca[tid] = pc; cb[tid] = nc;
        __syncthreads();
        for (int w = 128; w > 0; w >>= 1) {
            if (tid < w) {
                ra[tid] += ra[tid + w];
                rb[tid] += rb[tid + w];
                ca[tid] += ca[tid + w];
                cb[tid] += cb[tid + w];
            }
            __syncthreads();
        }
        if (tid == 0) {
            atomicAdd(&accf[1], ra[0]);
            atomicAdd(&accf[2], rb[0]);
            atomicAdd(&acci[0], ca[0]);
            atomicAdd(&acci[1], cb[0]);
        }
    }

    // last finished block computes the final outputs
    if (tid == 0) {
        __threadfence();
        int old = __hip_atomic_fetch_add(&acci[2], 1, __ATOMIC_ACQ_REL,
                                         __HIP_MEMORY_SCOPE_AGENT);
        if (old == GB_TOT - 1) {
            __threadfence();
            float cham = __hip_atomic_load(&accf[0], __ATOMIC_RELAXED, __HIP_MEMORY_SCOPE_AGENT);
            float pos  = __hip_atomic_load(&accf[1], __ATOMIC_RELAXED, __HIP_MEMORY_SCOPE_AGENT);
            float neg  = __hip_atomic_load(&accf[2], __ATOMIC_RELAXED, __HIP_MEMORY_SCOPE_AGENT);
            int cp = __hip_atomic_load(&acci[0], __ATOMIC_RELAXED, __HIP_MEMORY_SCOPE_AGENT);
            int cn = __hip_atomic_load(&acci[1], __ATOMIC_RELAXED, __HIP_MEMORY_SCOPE_AGENT);
            out[0] = cham * (1.0f / (float)NPTS);
            float loss = 0.0f;
            if (cp > 0) loss += pos / (float)cp;
            if (cn > 0) loss += neg / (float)cn;
            out[1] = loss;
        }
    }
}

// ---------------- launcher ----------------
extern "C" void kernel_launch(void* const* d_in, const int* in_sizes, int n_in,
                              void* d_out, int out_size, void* d_ws, size_t ws_size,
                              hipStream_t stream) {
    const float* pred_PM   = (const float*)d_in[0];
    const float* pred_Ms   = (const float*)d_in[1];
    const float* depth_src = (const float*)d_in[2];
    const float* depth_tgt = (const float*)d_in[3];
    float* out = (float*)d_out;

    int* mins = (int*)d_ws;                      // 2*NPTS ints
    float* accf = (float*)(mins + 2 * NPTS);     // 3 floats
    int* acci = (int*)(accf + 3);                // 3 ints

    init_k<<<(2 * NPTS + 255) / 256, 256, 0, stream>>>(mins, (int*)accf);
    chamfer_partial_k<<<dim3(CH_ABLK, CH_SCH, 2), CH_BT, 0, stream>>>(
        depth_src, depth_tgt, mins);
    finalize_k<<<GB_TOT, 256, 0, stream>>>(mins, pred_PM, pred_Ms, accf, acci, out);
}

// Round 3
// 78.377 us; speedup vs baseline: 1.7001x; 1.0771x over previous
//
#include <hip/hip_runtime.h>
#include <math.h>

// ---------------- problem constants ----------------
#define HH 120
#define WW 160
#define NPTS (HH * WW)            // 19200
#define FXC 572.4114f
#define FYC 573.57043f
#define CXC 325.2611f
#define CYC 242.04899f

// chamfer tiling
#define CH_BT   64                 // threads per block (1 wave)
#define CH_T    15                 // a-points per thread
#define CH_APB  (CH_BT * CH_T)     // 960 a-points per block
#define CH_ABLK (NPTS / CH_APB)    // 20 a-blocks
#define CH_BTILE 300               // b-points per LDS tile
#define CH_SCH  (NPTS / CH_BTILE)  // 64 b-chunks
// grid = 20 * 64 * 2 = 2560 one-wave blocks = 10 blocks/CU

#define MASK_WGT 1.3989422804014327f   // exp(0)*inv_sqrt_2pi + 1

// finalize kernel geometry
#define GB_CH 64                   // blocks doing chamfer sum
#define GB_MK 16                   // blocks doing mask loss
#define GB_TOT (GB_CH + GB_MK)
#define CH_SEG (2 * NPTS / GB_CH)  // 600 elements per chamfer block
#define MK_SEG (NPTS / GB_MK)      // 1200 elements per mask block

__device__ __forceinline__ void backproject_pt(int idx, float d,
                                               float& px, float& py, float& pz) {
    int y = idx / WW;
    int x = idx - y * WW;
    px = ((float)x - CXC) * d * (1.0f / FXC);
    py = ((float)y - CYC) * d * (1.0f / FYC);
    pz = d;
}

__device__ __forceinline__ float min3f(float a, float b, float c) {
    float d;
    asm("v_min3_f32 %0, %1, %2, %3" : "=v"(d) : "v"(a), "v"(b), "v"(c));
    return d;
}

// ---------------- kernel 1: init mins to +inf, zero accumulators ----------------
__global__ void __launch_bounds__(256) init_k(int* __restrict__ mins,
                                              int* __restrict__ accs) {
    int i = blockIdx.x * 256 + threadIdx.x;
    if (i < 2 * NPTS) mins[i] = 0x7F800000;  // +inf bit pattern
    if (i < 6) accs[i] = 0;                  // accf[3] + acci[3]
}

// ---------------- kernel 2: chamfer partial mins ----------------
// grid: (CH_ABLK, CH_SCH, 2). blockIdx.z selects direction.
__global__ void __launch_bounds__(CH_BT) chamfer_partial_k(
    const float* __restrict__ depth_src, const float* __restrict__ depth_tgt,
    int* __restrict__ mins_base) {
    const float* dA;
    const float* dB;
    int* mins;
    if (blockIdx.z == 0) { dA = depth_src; dB = depth_tgt; mins = mins_base; }
    else                 { dA = depth_tgt; dB = depth_src; mins = mins_base + NPTS; }

    __shared__ float4 bp[CH_BTILE];

    const int tid = threadIdx.x;
    const int ablk = blockIdx.x;
    const int s = blockIdx.y;

    // stage b tile: (2x, 2y, 2z, |b|^2)
    for (int jj = tid; jj < CH_BTILE; jj += CH_BT) {
        int j = s * CH_BTILE + jj;
        float d = dB[j];
        float px, py, pz;
        backproject_pt(j, d, px, py, pz);
        bp[jj] = make_float4(2.0f * px, 2.0f * py, 2.0f * pz,
                             fmaf(px, px, fmaf(py, py, pz * pz)));
    }

    // load a points into registers (negated for the fma chain)
    float nax[CH_T], nay[CH_T], naz[CH_T], a2[CH_T], mn[CH_T];
#pragma unroll
    for (int t = 0; t < CH_T; ++t) {
        int i = ablk * CH_APB + t * CH_BT + tid;
        float d = dA[i];
        float px, py, pz;
        backproject_pt(i, d, px, py, pz);
        a2[t] = fmaf(px, px, fmaf(py, py, pz * pz));
        nax[t] = -px; nay[t] = -py; naz[t] = -pz;
        mn[t] = INFINITY;  // tracks min over j of (b2_j - 2*dot_j)
    }

    __syncthreads();

    // 3 fma + 0.5 min3 per pair = 3.5 VALU ops/pair; 1 ds_read_b128 per b-point
    for (int jj = 0; jj < CH_BTILE; jj += 4) {
        float4 q0 = bp[jj + 0];
        float4 q1 = bp[jj + 1];
        float4 q2 = bp[jj + 2];
        float4 q3 = bp[jj + 3];
#pragma unroll
        for (int t = 0; t < CH_T; ++t) {
            float r0 = fmaf(nax[t], q0.x, fmaf(nay[t], q0.y, fmaf(naz[t], q0.z, q0.w)));
            float r1 = fmaf(nax[t], q1.x, fmaf(nay[t], q1.y, fmaf(naz[t], q1.z, q1.w)));
            float r2 = fmaf(nax[t], q2.x, fmaf(nay[t], q2.y, fmaf(naz[t], q2.z, q2.w)));
            float r3 = fmaf(nax[t], q3.x, fmaf(nay[t], q3.y, fmaf(naz[t], q3.z, q3.w)));
            mn[t] = min3f(mn[t], r0, r1);
            mn[t] = min3f(mn[t], r2, r3);
        }
    }

    // finalize: d = max(a2 + (b2 - 2ab), 0); combine across b-chunks via atomicMin.
    // max(.,0) commutes with min; values >= 0 so int ordering == float ordering.
#pragma unroll
    for (int t = 0; t < CH_T; ++t) {
        int i = ablk * CH_APB + t * CH_BT + tid;
        float v = fmaxf(a2[t] + mn[t], 0.0f);
        atomicMin(&mins[i], __float_as_int(v));
    }
}

// ---------------- kernel 3: fused reduction + mask loss -> out[0], out[1] ----------------
// accf[0]=cham_sum, accf[1]=pos_sum, accf[2]=neg_sum
// acci[0]=pos_cnt,  acci[1]=neg_cnt,  acci[2]=done_counter
__global__ void __launch_bounds__(256) finalize_k(const int* __restrict__ mins,
                                                  const float* __restrict__ pm,
                                                  const float* __restrict__ ms,
                                                  float* __restrict__ accf,
                                                  int* __restrict__ acci,
                                                  float* __restrict__ out) {
    const int b = blockIdx.x;
    const int tid = threadIdx.x;
    __shared__ float ra[256], rb[256];
    __shared__ int ca[256], cb[256];

    if (b < GB_CH) {
        // chamfer partial sum over a 600-element segment
        float s = 0.0f;
        int base = b * CH_SEG;
        for (int i = tid; i < CH_SEG; i += 256) s += __int_as_float(mins[base + i]);
        ra[tid] = s;
        __syncthreads();
        for (int w = 128; w > 0; w >>= 1) {
            if (tid < w) ra[tid] += ra[tid + w];
            __syncthreads();
        }
        if (tid == 0) atomicAdd(&accf[0], ra[0]);
    } else {
        // mask loss partial over a 1200-element segment
        int base = (b - GB_CH) * MK_SEG;
        float ps = 0.0f, ns = 0.0f;
        int pc = 0, nc = 0;
        for (int i = tid; i < MK_SEG; i += 256) {
            float p = pm[base + i];
            p = fminf(fmaxf(p, 1e-7f), 1.0f - 1e-7f);
            float t = ms[base + i];
            if (t > 0.0f) {
                ps += -t * logf(p) * MASK_WGT;
                pc++;
            } else if (t == 0.0f) {
                ns += -logf(1.0f - p) * MASK_WGT;
                nc++;
            }
        }
        ra[tid] = ps; rb[tid] = ns; ca[tid] = pc; cb[tid] = nc;
        __syncthreads();
        for (int w = 128; w > 0; w >>= 1) {
            if (tid < w) {
                ra[tid] += ra[tid + w];
                rb[tid] += rb[tid + w];
                ca[tid] += ca[tid + w];
                cb[tid] += cb[tid + w];
            }
            __syncthreads();
        }
        if (tid == 0) {
            atomicAdd(&accf[1], ra[0]);
            atomicAdd(&accf[2], rb[0]);
            atomicAdd(&acci[0], ca[0]);
            atomicAdd(&acci[1], cb[0]);
        }
    }

    // last finished block computes the final outputs
    if (tid == 0) {
        __threadfence();
        int old = __hip_atomic_fetch_add(&acci[2], 1, __ATOMIC_ACQ_REL,
                                         __HIP_MEMORY_SCOPE_AGENT);
        if (old == GB_TOT - 1) {
            __threadfence();
            float cham = __hip_atomic_load(&accf[0], __ATOMIC_RELAXED, __HIP_MEMORY_SCOPE_AGENT);
            float pos  = __hip_atomic_load(&accf[1], __ATOMIC_RELAXED, __HIP_MEMORY_SCOPE_AGENT);
            float neg  = __hip_atomic_load(&accf[2], __ATOMIC_RELAXED, __HIP_MEMORY_SCOPE_AGENT);
            int cp = __hip_atomic_load(&acci[0], __ATOMIC_RELAXED, __HIP_MEMORY_SCOPE_AGENT);
            int cn = __hip_atomic_load(&acci[1], __ATOMIC_RELAXED, __HIP_MEMORY_SCOPE_AGENT);
            out[0] = cham * (1.0f / (float)NPTS);
            float loss = 0.0f;
            if (cp > 0) loss += pos / (float)cp;
            if (cn > 0) loss += neg / (float)cn;
            out[1] = loss;
        }
    }
}

// ---------------- launcher ----------------
extern "C" void kernel_launch(void* const* d_in, const int* in_sizes, int n_in,
                              void* d_out, int out_size, void* d_ws, size_t ws_size,
                              hipStream_t stream) {
    const float* pred_PM   = (const float*)d_in[0];
    const float* pred_Ms   = (const float*)d_in[1];
    const float* depth_src = (const float*)d_in[2];
    const float* depth_tgt = (const float*)d_in[3];
    float* out = (float*)d_out;

    int* mins = (int*)d_ws;                      // 2*NPTS ints
    float* accf = (float*)(mins + 2 * NPTS);     // 3 floats
    int* acci = (int*)(accf + 3);                // 3 ints

    init_k<<<(2 * NPTS + 255) / 256, 256, 0, stream>>>(mins, (int*)accf);
    chamfer_partial_k<<<dim3(CH_ABLK, CH_SCH, 2), CH_BT, 0, stream>>>(
        depth_src, depth_tgt, mins);
    finalize_k<<<GB_TOT, 256, 0, stream>>>(mins, pred_PM, pred_Ms, accf, acci, out);
}

// Round 4
// 70.602 us; speedup vs baseline: 1.8873x; 1.1101x over previous
//
#include <hip/hip_runtime.h>
#include <math.h>

// ---------------- problem constants ----------------
#define HH 120
#define WW 160
#define NPTS (HH * WW)            // 19200
#define FXC 572.4114f
#define FYC 573.57043f
#define CXC 325.2611f
#define CYC 242.04899f

// chamfer tiling
#define CH_BT   64                 // threads per block (1 wave)
#define CH_T    10                 // a-points per thread
#define CH_APB  (CH_BT * CH_T)     // 640 a-points per block
#define CH_ABLK (NPTS / CH_APB)    // 30 a-blocks
#define CH_BTILE 192               // b-points per LDS tile (3 staging rows of 64)
#define CH_SCH  (NPTS / CH_BTILE)  // 100 b-chunks
// grid = 30 * 100 * 2 = 6000 one-wave blocks ~= 23/CU ~= 5.9 waves/SIMD

#define MASK_WGT 1.3989422804014327f   // exp(0)*inv_sqrt_2pi + 1

// finalize kernel geometry
#define GB_CH 64                   // blocks doing chamfer sum
#define GB_MK 16                   // blocks doing mask loss
#define GB_TOT (GB_CH + GB_MK)
#define CH_SEG (2 * NPTS / GB_CH)  // 600 elements per chamfer block
#define MK_SEG (NPTS / GB_MK)      // 1200 elements per mask block

__device__ __forceinline__ void backproject_pt(int idx, float d,
                                               float& px, float& py, float& pz) {
    int y = idx / WW;
    int x = idx - y * WW;
    px = ((float)x - CXC) * d * (1.0f / FXC);
    py = ((float)y - CYC) * d * (1.0f / FYC);
    pz = d;
}

__device__ __forceinline__ float min3f(float a, float b, float c) {
    float d;
    asm("v_min3_f32 %0, %1, %2, %3" : "=v"(d) : "v"(a), "v"(b), "v"(c));
    return d;
}

// ---------------- kernel 1: init mins to +inf, zero accumulators ----------------
__global__ void __launch_bounds__(256) init_k(int* __restrict__ mins,
                                              int* __restrict__ accs) {
    int i = blockIdx.x * 256 + threadIdx.x;
    if (i < 2 * NPTS) mins[i] = 0x7F800000;  // +inf bit pattern
    if (i < 6) accs[i] = 0;                  // accf[3] + acci[3]
}

// ---------------- kernel 2: chamfer partial mins ----------------
// grid: (CH_ABLK, CH_SCH, 2). blockIdx.z selects direction.
// Register budget (per thread): nax/nay/naz x10 = 30, mn x10 = 10, q0/q1 = 8,
// transients ~6, addr ~4  => ~58 live VGPRs. a2 is recomputed at finalize.
__global__ void __launch_bounds__(CH_BT, 6) chamfer_partial_k(
    const float* __restrict__ depth_src, const float* __restrict__ depth_tgt,
    int* __restrict__ mins_base) {
    const float* dA;
    const float* dB;
    int* mins;
    if (blockIdx.z == 0) { dA = depth_src; dB = depth_tgt; mins = mins_base; }
    else                 { dA = depth_tgt; dB = depth_src; mins = mins_base + NPTS; }

    __shared__ float4 bp[CH_BTILE];

    const int tid = threadIdx.x;
    const int ablk = blockIdx.x;
    const int s = blockIdx.y;

    // stage b tile: (2x, 2y, 2z, |b|^2) -- exactly 3 rows of 64
#pragma unroll
    for (int r = 0; r < CH_BTILE / CH_BT; ++r) {
        int jj = r * CH_BT + tid;
        int j = s * CH_BTILE + jj;
        float d = dB[j];
        float px, py, pz;
        backproject_pt(j, d, px, py, pz);
        bp[jj] = make_float4(2.0f * px, 2.0f * py, 2.0f * pz,
                             fmaf(px, px, fmaf(py, py, pz * pz)));
    }

    // load a points into registers (negated for the fma chain)
    float nax[CH_T], nay[CH_T], naz[CH_T], mn[CH_T];
#pragma unroll
    for (int t = 0; t < CH_T; ++t) {
        int i = ablk * CH_APB + t * CH_BT + tid;
        float d = dA[i];
        float px, py, pz;
        backproject_pt(i, d, px, py, pz);
        nax[t] = -px; nay[t] = -py; naz[t] = -pz;
        mn[t] = INFINITY;  // tracks min over j of (b2_j - 2*dot_j)
    }

    __syncthreads();

    // 3 fma per pair + 1 min3 per 2 pairs = 3.5 VALU ops/pair.
    // Only two float4 q's live at a time -> low register pressure.
    for (int jj = 0; jj < CH_BTILE; jj += 2) {
        float4 q0 = bp[jj + 0];
        float4 q1 = bp[jj + 1];
#pragma unroll
        for (int t = 0; t < CH_T; ++t) {
            float r0 = fmaf(nax[t], q0.x, fmaf(nay[t], q0.y, fmaf(naz[t], q0.z, q0.w)));
            float r1 = fmaf(nax[t], q1.x, fmaf(nay[t], q1.y, fmaf(naz[t], q1.z, q1.w)));
            mn[t] = min3f(mn[t], r0, r1);
        }
    }

    // finalize: d = max(a2 + (b2 - 2ab), 0); a2 recomputed here (3 fma).
    // max(.,0) commutes with min; values >= 0 so int ordering == float ordering.
#pragma unroll
    for (int t = 0; t < CH_T; ++t) {
        int i = ablk * CH_APB + t * CH_BT + tid;
        float a2 = fmaf(nax[t], nax[t], fmaf(nay[t], nay[t], naz[t] * naz[t]));
        float v = fmaxf(a2 + mn[t], 0.0f);
        atomicMin(&mins[i], __float_as_int(v));
    }
}

// ---------------- kernel 3: fused reduction + mask loss -> out[0], out[1] ----------------
// accf[0]=cham_sum, accf[1]=pos_sum, accf[2]=neg_sum
// acci[0]=pos_cnt,  acci[1]=neg_cnt,  acci[2]=done_counter
__global__ void __launch_bounds__(256) finalize_k(const int* __restrict__ mins,
                                                  const float* __restrict__ pm,
                                                  const float* __restrict__ ms,
                                                  float* __restrict__ accf,
                                                  int* __restrict__ acci,
                                                  float* __restrict__ out) {
    const int b = blockIdx.x;
    const int tid = threadIdx.x;
    __shared__ float ra[256], rb[256];
    __shared__ int ca[256], cb[256];

    if (b < GB_CH) {
        // chamfer partial sum over a 600-element segment
        float s = 0.0f;
        int base = b * CH_SEG;
        for (int i = tid; i < CH_SEG; i += 256) s += __int_as_float(mins[base + i]);
        ra[tid] = s;
        __syncthreads();
        for (int w = 128; w > 0; w >>= 1) {
            if (tid < w) ra[tid] += ra[tid + w];
            __syncthreads();
        }
        if (tid == 0) atomicAdd(&accf[0], ra[0]);
    } else {
        // mask loss partial over a 1200-element segment
        int base = (b - GB_CH) * MK_SEG;
        float ps = 0.0f, ns = 0.0f;
        int pc = 0, nc = 0;
        for (int i = tid; i < MK_SEG; i += 256) {
            float p = pm[base + i];
            p = fminf(fmaxf(p, 1e-7f), 1.0f - 1e-7f);
            float t = ms[base + i];
            if (t > 0.0f) {
                ps += -t * logf(p) * MASK_WGT;
                pc++;
            } else if (t == 0.0f) {
                ns += -logf(1.0f - p) * MASK_WGT;
                nc++;
            }
        }
        ra[tid] = ps; rb[tid] = ns; ca[tid] = pc; cb[tid] = nc;
        __syncthreads();
        for (int w = 128; w > 0; w >>= 1) {
            if (tid < w) {
                ra[tid] += ra[tid + w];
                rb[tid] += rb[tid + w];
                ca[tid] += ca[tid + w];
                cb[tid] += cb[tid + w];
            }
            __syncthreads();
        }
        if (tid == 0) {
            atomicAdd(&accf[1], ra[0]);
            atomicAdd(&accf[2], rb[0]);
            atomicAdd(&acci[0], ca[0]);
            atomicAdd(&acci[1], cb[0]);
        }
    }

    // last finished block computes the final outputs
    if (tid == 0) {
        __threadfence();
        int old = __hip_atomic_fetch_add(&acci[2], 1, __ATOMIC_ACQ_REL,
                                         __HIP_MEMORY_SCOPE_AGENT);
        if (old == GB_TOT - 1) {
            __threadfence();
            float cham = __hip_atomic_load(&accf[0], __ATOMIC_RELAXED, __HIP_MEMORY_SCOPE_AGENT);
            float pos  = __hip_atomic_load(&accf[1], __ATOMIC_RELAXED, __HIP_MEMORY_SCOPE_AGENT);
            float neg  = __hip_atomic_load(&accf[2], __ATOMIC_RELAXED, __HIP_MEMORY_SCOPE_AGENT);
            int cp = __hip_atomic_load(&acci[0], __ATOMIC_RELAXED, __HIP_MEMORY_SCOPE_AGENT);
            int cn = __hip_atomic_load(&acci[1], __ATOMIC_RELAXED, __HIP_MEMORY_SCOPE_AGENT);
            out[0] = cham * (1.0f / (float)NPTS);
            float loss = 0.0f;
            if (cp > 0) loss += pos / (float)cp;
            if (cn > 0) loss += neg / (float)cn;
            out[1] = loss;
        }
    }
}

// ---------------- launcher ----------------
extern "C" void kernel_launch(void* const* d_in, const int* in_sizes, int n_in,
                              void* d_out, int out_size, void* d_ws, size_t ws_size,
                              hipStream_t stream) {
    const float* pred_PM   = (const float*)d_in[0];
    const float* pred_Ms   = (const float*)d_in[1];
    const float* depth_src = (const float*)d_in[2];
    const float* depth_tgt = (const float*)d_in[3];
    float* out = (float*)d_out;

    int* mins = (int*)d_ws;                      // 2*NPTS ints
    float* accf = (float*)(mins + 2 * NPTS);     // 3 floats
    int* acci = (int*)(accf + 3);                // 3 ints

    init_k<<<(2 * NPTS + 255) / 256, 256, 0, stream>>>(mins, (int*)accf);
    chamfer_partial_k<<<dim3(CH_ABLK, CH_SCH, 2), CH_BT, 0, stream>>>(
        depth_src, depth_tgt, mins);
    finalize_k<<<GB_TOT, 256, 0, stream>>>(mins, pred_PM, pred_Ms, accf, acci, out);
}